// Round 7
// baseline (534.210 us; speedup 1.0000x reference)
//
#include <hip/hip_runtime.h>
#include <math.h>

#define HW 784      // 28*28
#define TSTEPS 30

struct GaussW { float w[7]; };

// Exact-rounded f32 ops (never fused/contracted) to bitwise-match numpy f32.
__device__ __forceinline__ float fadd(float a, float b) { return __fadd_rn(a, b); }
__device__ __forceinline__ float fmul(float a, float b) { return __fmul_rn(a, b); }
__device__ __forceinline__ float fsub(float a, float b) { return __fsub_rn(a, b); }

// 1-instruction bitfield extracts (v_bfe_i32 / v_bfe_u32) with portable fallback
#if defined(__has_builtin)
#  if __has_builtin(__builtin_amdgcn_sbfe)
#    define SBFE(x, b) __builtin_amdgcn_sbfe((int)(x), (unsigned)(b), 1u)
#  endif
#  if __has_builtin(__builtin_amdgcn_ubfe)
#    define UBFE(x, o, w) __builtin_amdgcn_ubfe((unsigned)(x), (unsigned)(o), (unsigned)(w))
#  endif
#endif
#ifndef SBFE
#  define SBFE(x, b) (((int)((unsigned)(x) << (31 - (b)))) >> 31)
#endif
#ifndef UBFE
#  define UBFE(x, o, w) (((unsigned)(x) >> (o)) & ((1u << (w)) - 1u))
#endif

// w if bit b of rw set else +0.0f; fadd(acc, this) == fadd(acc, fmul(w, spike))
// bitwise, for spike in {0,1} (+0.0 add is identity, product exact).
#define SELW(rw, b, w) __int_as_float(SBFE((rw), (b)) & __float_as_int(w))

__device__ __forceinline__ int refl(int i, int n) {
    if (i < 0) return -i - 1;
    if (i >= n) return 2 * n - 1 - i;
    return i;
}

// d[p] = |gauss4d(x)[b,p] - x[b,p]| into dout (784 floats in LDS), bit-exact
// numpy-f32 order: axis0 (batch), axis1 (size-1 channel), axis2, axis3.
__device__ void dog_sample(const float* __restrict__ x, int b, int nbatch,
                           const GaussW gw, float* g, float* t,
                           float* dout, int tid) {
    for (int p = tid; p < HW; p += 256) {
        float acc = fmul(gw.w[0], x[(size_t)refl(b - 3, nbatch) * HW + p]);
        #pragma unroll
        for (int k = 1; k < 7; ++k)
            acc = fadd(acc, fmul(gw.w[k], x[(size_t)refl(b - 3 + k, nbatch) * HW + p]));
        float h = fmul(gw.w[0], acc);   // axis 1: size-1 dim, all slices equal
        #pragma unroll
        for (int k = 1; k < 7; ++k)
            h = fadd(h, fmul(gw.w[k], acc));
        g[p] = h;
    }
    __syncthreads();
    for (int p = tid; p < HW; p += 256) {
        int i = p / 28, j = p - (p / 28) * 28;
        float acc = fmul(gw.w[0], g[refl(i - 3, 28) * 28 + j]);
        #pragma unroll
        for (int k = 1; k < 7; ++k)
            acc = fadd(acc, fmul(gw.w[k], g[refl(i - 3 + k, 28) * 28 + j]));
        t[p] = acc;
    }
    __syncthreads();
    for (int p = tid; p < HW; p += 256) {
        int i = p / 28, j = p - (p / 28) * 28;
        float acc = fmul(gw.w[0], t[i * 28 + refl(j - 3, 28)]);
        #pragma unroll
        for (int k = 1; k < 7; ++k)
            acc = fadd(acc, fmul(gw.w[k], t[i * 28 + refl(j - 3 + k, 28)]));
        dout[p] = fabsf(fsub(acc, x[(size_t)b * HW + p]));
    }
    __syncthreads();
}

__global__ void init_kernel(unsigned int* dmax) { *dmax = 0u; }

template<bool CACHE>
__global__ __launch_bounds__(256) void dmax_kernel(const float* __restrict__ x,
                                                   int nbatch, GaussW gw,
                                                   unsigned int* __restrict__ dmax,
                                                   float* __restrict__ dcache) {
    __shared__ float g[HW], t[HW], d[HW];
    __shared__ float wred[4];
    int tid = threadIdx.x;
    int b = blockIdx.x;
    dog_sample(x, b, nbatch, gw, g, t, d, tid);
    if (CACHE)
        for (int p = tid; p < HW; p += 256) dcache[(size_t)b * HW + p] = d[p];
    float m = 0.f;
    for (int p = tid; p < HW; p += 256) m = fmaxf(m, d[p]);
    #pragma unroll
    for (int off = 32; off; off >>= 1) m = fmaxf(m, __shfl_down(m, off, 64));
    if ((tid & 63) == 0) wred[tid >> 6] = m;
    __syncthreads();
    if (tid == 0) {
        m = fmaxf(fmaxf(wred[0], wred[1]), fmaxf(wred[2], wred[3]));
        atomicMax(dmax, __float_as_uint(m));  // d >= 0 so bit-max == float-max
    }
}

template<bool CACHE>
__global__ __launch_bounds__(256) void sim_kernel(const float* __restrict__ x,
        int nbatch,
        const float* __restrict__ w1g, const float* __restrict__ w2g,
        const float* __restrict__ w3g, GaussW gw,
        const unsigned int* __restrict__ dmaxp,
        const float* __restrict__ dcache,
        float* __restrict__ out) {
    __shared__ __align__(16) float4 lut[512];   // conv1 LUT; DoG scratch pre-loop
    __shared__ __align__(16) float dn[HW];      // normalized DoG input
    __shared__ unsigned s1m[2][28];             // layer-1 spike row masks (dbuf)
    __shared__ unsigned p1m[2][52];             // pooled-1 masks [4c][13r], bits<<1
    __shared__ unsigned p2m[2][24];             // pooled-2 masks [4c][6r], bits 0..5
    __shared__ float wts[216];                  // w1(36) | w2(144) | w3(36)

    int tid = threadIdx.x;
    int b = blockIdx.x;

    // ---------------- fixed geometry ----------------
    // conv1: items e = tid + 256k (k<3, e<676): (c, pooled pi,pj)
    int c1_[3], srow_[3], sh1_[3], pw1_[3]; unsigned pb1_[3];
    #pragma unroll
    for (int k = 0; k < 3; ++k) {
        int e = tid + (k << 8); if (e >= 676) e = 0;   // dummy; guarded at use
        int c = e / 169, r = e - c * 169;
        int pi = r / 13, pj = r - (r / 13) * 13;
        c1_[k] = c; srow_[k] = 2 * pi; sh1_[k] = 2 * pj;
        pw1_[k] = c * 13 + pi; pb1_[k] = 1u << (pj + 1);
    }
    // conv2: one item per thread; 44 (c,i)-rows of 11 cells.
    //   rows 0..35 : 5 pairs (jp0=0,2,4,6,8) + 1 single (jp0=10)   -> 6 items
    //   rows 36..43: 4 pairs (jp0=0,2,4,6)   + 1 triple (jp0=8)    -> 5 items
    int c2, i2, jp0, ncell2;
    {
        int rowid, sub;
        if (tid < 216) {
            rowid = tid / 6; sub = tid - rowid * 6;
            jp0 = (sub < 5) ? 2 * sub : 10; ncell2 = (sub < 5) ? 2 : 1;
        } else {
            int u = tid - 216; int r5 = u / 5; sub = u - r5 * 5;
            rowid = 36 + r5;
            jp0 = (sub < 4) ? 2 * sub : 8; ncell2 = (sub < 4) ? 2 : 3;
        }
        c2 = rowid / 11; i2 = rowid - c2 * 11;
    }
    int js2 = jp0 + 1;
    int p2w2 = c2 * 6 + ((i2 + 1) >> 1);
    unsigned p2bA = 1u << (jp0 >> 1);           // cell0
    unsigned p2bB = 1u << ((jp0 >> 1) + 1);     // cells 1,2 (share pooled col)
    // layer1: pixels e = tid + 256k (k<4, e<784)
    int l1w_[4]; unsigned l1b_[4];
    #pragma unroll
    for (int k = 0; k < 4; ++k) {
        int e = tid + (k << 8); if (e >= HW) e = 0;
        int rw = e / 28;
        l1w_[k] = rw; l1b_[k] = 1u << (e - rw * 28);
    }

    // ---------------- membranes (registers) ----------------
    float v2q[3][4] = {{0.f,0.f,0.f,0.f},{0.f,0.f,0.f,0.f},{0.f,0.f,0.f,0.f}};
    float v3m[3] = {0.f, 0.f, 0.f};
    float v1m[4] = {0.f, 0.f, 0.f, 0.f};
    float v4 = 0.f, pred = 0.f;

    // ---------------- init phase 0: weights + dn ----------------
    if (tid < 36)  wts[tid]       = w1g[tid];
    if (tid < 144) wts[36 + tid]  = w2g[tid];
    if (tid < 36)  wts[180 + tid] = w3g[tid];
    float dmax = __uint_as_float(*dmaxp);
    if (CACHE) {
        for (int p = tid; p < HW; p += 256)
            dn[p] = __fdiv_rn(dcache[(size_t)b * HW + p], dmax);
    } else {
        float* scr = (float*)lut;   // 2048 floats >= 2*784
        dog_sample(x, b, nbatch, gw, scr, scr + HW, dn, tid);
        for (int p = tid; p < HW; p += 256) dn[p] = __fdiv_rn(dn[p], dmax);
    }
    __syncthreads();

    // ---------------- init phase 1: conv1 LUT + zero t=0 masks ----------------
    for (int e = tid; e < 512; e += 256) {
        float a0 = 0.f, a1 = 0.f, a2 = 0.f, a3 = 0.f;
        #pragma unroll
        for (int k = 0; k < 9; ++k) {
            bool bit = (e >> k) & 1;
            a0 = fadd(a0, bit ? wts[k]      : 0.0f);
            a1 = fadd(a1, bit ? wts[9 + k]  : 0.0f);
            a2 = fadd(a2, bit ? wts[18 + k] : 0.0f);
            a3 = fadd(a3, bit ? wts[27 + k] : 0.0f);
        }
        lut[e] = make_float4(a0, a1, a2, a3);
    }
    if (tid < 28) s1m[0][tid] = 0u;
    else if (tid < 80) p1m[0][tid - 28] = 0u;
    __syncthreads();

    // ---------------- per-thread constants ----------------
    float dnr[4];
    #pragma unroll
    for (int k = 0; k < 4; ++k) {
        int e = tid + (k << 8);
        dnr[k] = (e < HW) ? dn[e] : 0.f;
    }
    float w2r[36];
    #pragma unroll
    for (int m = 0; m < 36; ++m) w2r[m] = wts[36 + c2 * 36 + m];

    // ---------------- layer1(0) -> s1m[0] ----------------
    #pragma unroll
    for (int k = 0; k < 4; ++k) {
        if (k < 3 || tid < 16) {
            float v = fadd(v1m[k], dnr[k]);
            bool spk = v >= 4.5f;
            v1m[k] = spk ? 0.f : v;
            if (spk) atomicOr(&s1m[0][l1w_[k]], l1b_[k]);
        }
    }
    __syncthreads();

    const float* lutf = (const float*)lut;

    for (int t = 0; t < TSTEPS; ++t) {
        int cur = t & 1, nxt = cur ^ 1;
        // ==== phase B: conv1(t) [all] | conv3(t-1) | zero s1m/p2m/p1m[nxt] ====
        {
            const unsigned* sm = s1m[cur];
            unsigned* pm = p1m[cur];
            #pragma unroll
            for (int k = 0; k < 3; ++k) {
                if (k < 2 || tid < 164) {
                    int sr = srow_[k], sh = sh1_[k];
                    unsigned m0 = sm[sr], m1 = sm[sr + 1], m2 = sm[sr + 2], m3 = sm[sr + 3];
                    unsigned cb = 0;
                    #pragma unroll
                    for (int di = 0; di < 2; ++di) {
                        unsigned ra = di ? m1 : m0, rb = di ? m2 : m1, rc = di ? m3 : m2;
                        #pragma unroll
                        for (int dj = 0; dj < 2; ++dj) {
                            unsigned s = (unsigned)(sh + dj);
                            unsigned pat = UBFE(ra, s, 3) | (UBFE(rb, s, 3) << 3)
                                         | (UBFE(rc, s, 3) << 6);
                            float a = lutf[(pat << 2) + c1_[k]];
                            float v = fadd(v2q[k][di * 2 + dj], a);
                            bool spk = v >= 4.5f;
                            v2q[k][di * 2 + dj] = spk ? 0.f : v;
                            cb |= (unsigned)spk;
                        }
                    }
                    if (cb) atomicOr(&pm[pw1_[k]], pb1_[k]);
                }
            }
            if (tid >= 164 && tid < 192) s1m[nxt][tid - 164] = 0u;
            if (tid >= 192 && tid < 216) p2m[cur][tid - 192] = 0u;
            if (tid >= 216 && tid < 240) {
                for (int w = tid - 216; w < 52; w += 24) p1m[nxt][w] = 0u;
            }
            if (t > 0 && tid >= 240) {
                int qq = tid - 240, rr = qq >> 2, cc = qq & 3;
                const unsigned* zm = p2m[nxt];   // p2m[(t-1)&1]
                float acc = 0.f;
                #pragma unroll
                for (int ic = 0; ic < 4; ++ic)
                    #pragma unroll
                    for (int ki = 0; ki < 3; ++ki) {
                        unsigned rw = zm[ic * 6 + rr + ki] >> (unsigned)cc;
                        #pragma unroll
                        for (int kj = 0; kj < 3; ++kj)
                            acc = fadd(acc, SELW(rw, kj, wts[180 + ic * 9 + ki * 3 + kj]));
                    }
                v4 = fadd(v4, fmul(fsub(acc, v4), 0.5f));
                if (v4 >= 1.0f) { pred += 1.f; v4 = 0.f; }
            }
        }
        __syncthreads();

        // ==== phase A: conv2(t) [all, 1 item] || layer1(t+1) [all] ====
        {
            const unsigned* pmr = p1m[cur];
            float a0 = v3m[0], a1 = v3m[1], a2 = v3m[2];
            #pragma unroll
            for (int ic = 0; ic < 4; ++ic) {
                #pragma unroll
                for (int ki = 0; ki < 3; ++ki) {
                    unsigned rw = pmr[ic * 13 + i2 + ki] >> (unsigned)js2;
                    int w0 = __float_as_int(w2r[ic * 9 + ki * 3 + 0]);
                    int w1 = __float_as_int(w2r[ic * 9 + ki * 3 + 1]);
                    int w2i = __float_as_int(w2r[ic * 9 + ki * 3 + 2]);
                    int m0 = SBFE(rw, 0), m1 = SBFE(rw, 1), m2 = SBFE(rw, 2);
                    a0 = fadd(a0, __int_as_float(m0 & w0));
                    a0 = fadd(a0, __int_as_float(m1 & w1));
                    a0 = fadd(a0, __int_as_float(m2 & w2i));
                    if (ncell2 >= 2) {
                        int m3 = SBFE(rw, 3);
                        a1 = fadd(a1, __int_as_float(m1 & w0));
                        a1 = fadd(a1, __int_as_float(m2 & w1));
                        a1 = fadd(a1, __int_as_float(m3 & w2i));
                        if (ncell2 == 3) {
                            int m4 = SBFE(rw, 4);
                            a2 = fadd(a2, __int_as_float(m2 & w0));
                            a2 = fadd(a2, __int_as_float(m3 & w1));
                            a2 = fadd(a2, __int_as_float(m4 & w2i));
                        }
                    }
                }
            }
            unsigned orm = 0u;
            { bool s = a0 >= 1.0f; v3m[0] = s ? 0.f : a0; if (s) orm |= p2bA; }
            if (ncell2 >= 2) { bool s = a1 >= 1.0f; v3m[1] = s ? 0.f : a1; if (s) orm |= p2bB; }
            if (ncell2 == 3) { bool s = a2 >= 1.0f; v3m[2] = s ? 0.f : a2; if (s) orm |= p2bB; }
            if (orm) atomicOr(&p2m[cur][p2w2], orm);

            if (t < TSTEPS - 1) {
                unsigned* sn = s1m[nxt];
                #pragma unroll
                for (int k = 0; k < 4; ++k) {
                    if (k < 3 || tid < 16) {
                        float v = fadd(v1m[k], dnr[k]);
                        bool spk = v >= 4.5f;
                        v1m[k] = spk ? 0.f : v;
                        if (spk) atomicOr(&sn[l1w_[k]], l1b_[k]);
                    }
                }
            }
        }
        __syncthreads();
    }

    // ---------------- epilogue: conv3(29) + output ----------------
    if (tid >= 240) {
        int qq = tid - 240, rr = qq >> 2, cc = qq & 3;
        const unsigned* zm = p2m[(TSTEPS - 1) & 1];
        float acc = 0.f;
        #pragma unroll
        for (int ic = 0; ic < 4; ++ic)
            #pragma unroll
            for (int ki = 0; ki < 3; ++ki) {
                unsigned rw = zm[ic * 6 + rr + ki] >> (unsigned)cc;
                #pragma unroll
                for (int kj = 0; kj < 3; ++kj)
                    acc = fadd(acc, SELW(rw, kj, wts[180 + ic * 9 + ki * 3 + kj]));
            }
        v4 = fadd(v4, fmul(fsub(acc, v4), 0.5f));
        if (v4 >= 1.0f) { pred += 1.f; v4 = 0.f; }
        out[(size_t)b * 16 + qq] = __fdiv_rn(pred, 30.0f);
    }
}

extern "C" void kernel_launch(void* const* d_in, const int* in_sizes, int n_in,
                              void* d_out, int out_size, void* d_ws, size_t ws_size,
                              hipStream_t stream) {
    const float* x  = (const float*)d_in[0];
    const float* w1 = (const float*)d_in[1];
    const float* w2 = (const float*)d_in[2];
    const float* w3 = (const float*)d_in[3];
    float* out = (float*)d_out;
    unsigned int* dmax = (unsigned int*)d_ws;
    float* dcache = (float*)((char*)d_ws + 16);

    int nbatch = in_sizes[0] / HW;
    size_t need = 16 + (size_t)nbatch * HW * sizeof(float);
    bool cache = ws_size >= need;

    // numpy-f32 Gaussian weights: exact f32 steps + correctly-rounded exp
    GaussW gw;
    {
        float fw[7];
        for (int k = 0; k < 7; ++k) {
            float iv = (float)(k - 3);
            float q = iv / 2.0f;
            float e = -0.5f * (q * q);
            fw[k] = (float)exp((double)e);
        }
        float s = 0.0f;
        for (int k = 0; k < 7; ++k) s += fw[k];
        for (int k = 0; k < 7; ++k) gw.w[k] = fw[k] / s;
    }

    hipLaunchKernelGGL(init_kernel, dim3(1), dim3(1), 0, stream, dmax);
    if (cache) {
        hipLaunchKernelGGL(dmax_kernel<true>, dim3(nbatch), dim3(256), 0, stream,
                           x, nbatch, gw, dmax, dcache);
        hipLaunchKernelGGL(sim_kernel<true>, dim3(nbatch), dim3(256), 0, stream,
                           x, nbatch, w1, w2, w3, gw, dmax, dcache, out);
    } else {
        hipLaunchKernelGGL(dmax_kernel<false>, dim3(nbatch), dim3(256), 0, stream,
                           x, nbatch, gw, dmax, dcache);
        hipLaunchKernelGGL(sim_kernel<false>, dim3(nbatch), dim3(256), 0, stream,
                           x, nbatch, w1, w2, w3, gw, dmax, dcache, out);
    }
}

// Round 8
// 440.399 us; speedup vs baseline: 1.2130x; 1.2130x over previous
//
#include <hip/hip_runtime.h>
#include <math.h>

#define HW 784      // 28*28
#define TSTEPS 30

struct GaussW { float w[7]; };

// Exact-rounded f32 ops (never fused/contracted) to bitwise-match numpy f32.
__device__ __forceinline__ float fadd(float a, float b) { return __fadd_rn(a, b); }
__device__ __forceinline__ float fmul(float a, float b) { return __fmul_rn(a, b); }
__device__ __forceinline__ float fsub(float a, float b) { return __fsub_rn(a, b); }

// 1-instruction bitfield extracts (v_bfe_i32 / v_bfe_u32) with portable fallback
#if defined(__has_builtin)
#  if __has_builtin(__builtin_amdgcn_sbfe)
#    define SBFE(x, b) __builtin_amdgcn_sbfe((int)(x), (unsigned)(b), 1u)
#  endif
#  if __has_builtin(__builtin_amdgcn_ubfe)
#    define UBFE(x, o, w) __builtin_amdgcn_ubfe((unsigned)(x), (unsigned)(o), (unsigned)(w))
#  endif
#endif
#ifndef SBFE
#  define SBFE(x, b) (((int)((unsigned)(x) << (31 - (b)))) >> 31)
#endif
#ifndef UBFE
#  define UBFE(x, o, w) (((unsigned)(x) >> (o)) & ((1u << (w)) - 1u))
#endif

// w if bit b of rw set else +0.0f; fadd(acc, this) == fadd(acc, fmul(w, spike))
// bitwise, for spike in {0,1} (+0.0 add is identity, product exact).
#define SELW(rw, b, w) __int_as_float(SBFE((rw), (b)) & __float_as_int(w))

__device__ __forceinline__ int refl(int i, int n) {
    if (i < 0) return -i - 1;
    if (i >= n) return 2 * n - 1 - i;
    return i;
}

// d[p] = |gauss4d(x)[b,p] - x[b,p]| into dout (784 floats in LDS), bit-exact
// numpy-f32 order: axis0 (batch), axis1 (size-1 channel), axis2, axis3.
__device__ void dog_sample(const float* __restrict__ x, int b, int nbatch,
                           const GaussW gw, float* g, float* t,
                           float* dout, int tid) {
    for (int p = tid; p < HW; p += 256) {
        float acc = fmul(gw.w[0], x[(size_t)refl(b - 3, nbatch) * HW + p]);
        #pragma unroll
        for (int k = 1; k < 7; ++k)
            acc = fadd(acc, fmul(gw.w[k], x[(size_t)refl(b - 3 + k, nbatch) * HW + p]));
        float h = fmul(gw.w[0], acc);   // axis 1: size-1 dim, all slices equal
        #pragma unroll
        for (int k = 1; k < 7; ++k)
            h = fadd(h, fmul(gw.w[k], acc));
        g[p] = h;
    }
    __syncthreads();
    for (int p = tid; p < HW; p += 256) {
        int i = p / 28, j = p - (p / 28) * 28;
        float acc = fmul(gw.w[0], g[refl(i - 3, 28) * 28 + j]);
        #pragma unroll
        for (int k = 1; k < 7; ++k)
            acc = fadd(acc, fmul(gw.w[k], g[refl(i - 3 + k, 28) * 28 + j]));
        t[p] = acc;
    }
    __syncthreads();
    for (int p = tid; p < HW; p += 256) {
        int i = p / 28, j = p - (p / 28) * 28;
        float acc = fmul(gw.w[0], t[i * 28 + refl(j - 3, 28)]);
        #pragma unroll
        for (int k = 1; k < 7; ++k)
            acc = fadd(acc, fmul(gw.w[k], t[i * 28 + refl(j - 3 + k, 28)]));
        dout[p] = fabsf(fsub(acc, x[(size_t)b * HW + p]));
    }
    __syncthreads();
}

__global__ void init_kernel(unsigned int* dmax) { *dmax = 0u; }

template<bool CACHE>
__global__ __launch_bounds__(256) void dmax_kernel(const float* __restrict__ x,
                                                   int nbatch, GaussW gw,
                                                   unsigned int* __restrict__ dmax,
                                                   float* __restrict__ dcache) {
    __shared__ float g[HW], t[HW], d[HW];
    __shared__ float wred[4];
    int tid = threadIdx.x;
    int b = blockIdx.x;
    dog_sample(x, b, nbatch, gw, g, t, d, tid);
    if (CACHE)
        for (int p = tid; p < HW; p += 256) dcache[(size_t)b * HW + p] = d[p];
    float m = 0.f;
    for (int p = tid; p < HW; p += 256) m = fmaxf(m, d[p]);
    #pragma unroll
    for (int off = 32; off; off >>= 1) m = fmaxf(m, __shfl_down(m, off, 64));
    if ((tid & 63) == 0) wred[tid >> 6] = m;
    __syncthreads();
    if (tid == 0) {
        m = fmaxf(fmaxf(wred[0], wred[1]), fmaxf(wred[2], wred[3]));
        atomicMax(dmax, __float_as_uint(m));  // d >= 0 so bit-max == float-max
    }
}

template<bool CACHE>
__global__ __launch_bounds__(256) void sim_kernel(const float* __restrict__ x,
        int nbatch,
        const float* __restrict__ w1g, const float* __restrict__ w2g,
        const float* __restrict__ w3g, GaussW gw,
        const unsigned int* __restrict__ dmaxp,
        const float* __restrict__ dcache,
        float* __restrict__ out) {
    __shared__ __align__(16) float4 lut[512];   // conv1 LUT; DoG scratch pre-loop
    __shared__ __align__(16) float dn[HW];      // normalized DoG input
    __shared__ unsigned s1m[84];                // 3 bufs x 28 rows (layer-1 spikes)
    __shared__ unsigned p1m[156];               // 3 bufs x 52 (4c x 13r, bits<<1)
    __shared__ unsigned p2m[72];                // 3 bufs x 24 (4c x 6r)
    __shared__ float wts[216];                  // w1(36) | w2(144) | w3(36)

    int tid = threadIdx.x;
    int b = blockIdx.x;

    // ---------------- fixed geometry ----------------
    // conv1: items e = tid + 256k (k<3, e<676): (c, pooled pi,pj)
    int c1_[3], srow_[3], sh1_[3], pw1_[3]; unsigned pb1_[3];
    #pragma unroll
    for (int k = 0; k < 3; ++k) {
        int e = tid + (k << 8); if (e >= 676) e = 0;   // dummy; guarded at use
        int c = e / 169, r = e - c * 169;
        int pi = r / 13, pj = r - (r / 13) * 13;
        c1_[k] = c; srow_[k] = 2 * pi; sh1_[k] = 2 * pj;
        pw1_[k] = c * 13 + pi; pb1_[k] = 1u << (pj + 1);
    }
    // conv2 (r6 mapping): tid<240: c2=tid/60, cells r=2q,2q+1; tids 240-243: r=120
    bool cv2a = tid < 244, cv2b = tid < 240;
    int c2 = cv2b ? (tid / 60) : (cv2a ? tid - 240 : 0);
    int q2 = cv2b ? (tid - c2 * 60) : 60;
    int prow_[2], jsh_[2], p2w_[2]; unsigned p2b_[2];
    #pragma unroll
    for (int k = 0; k < 2; ++k) {
        int r = 2 * q2 + k; if (r > 120) r = 120;
        int i = r / 11, j = r - (r / 11) * 11;
        prow_[k] = i; jsh_[k] = j + 1;
        p2w_[k] = c2 * 6 + ((i + 1) >> 1); p2b_[k] = 1u << ((j + 1) >> 1);
    }
    // layer1: pixels e = tid + 256k (k<4, e<784)
    int l1w_[4]; unsigned l1b_[4];
    #pragma unroll
    for (int k = 0; k < 4; ++k) {
        int e = tid + (k << 8); if (e >= HW) e = 0;
        int rw = e / 28;
        l1w_[k] = rw; l1b_[k] = 1u << (e - rw * 28);
    }

    // ---------------- membranes (registers) ----------------
    float v2q[3][4] = {{0.f,0.f,0.f,0.f},{0.f,0.f,0.f,0.f},{0.f,0.f,0.f,0.f}};
    float v3m[2] = {0.f, 0.f};
    float v1m[4] = {0.f, 0.f, 0.f, 0.f};
    float v4 = 0.f, pred = 0.f;

    // ---------------- init phase 0: weights + dn ----------------
    if (tid < 36)  wts[tid]       = w1g[tid];
    if (tid < 144) wts[36 + tid]  = w2g[tid];
    if (tid < 36)  wts[180 + tid] = w3g[tid];
    float dmax = __uint_as_float(*dmaxp);
    if (CACHE) {
        for (int p = tid; p < HW; p += 256)
            dn[p] = __fdiv_rn(dcache[(size_t)b * HW + p], dmax);
    } else {
        float* scr = (float*)lut;   // 2048 floats >= 2*784
        dog_sample(x, b, nbatch, gw, scr, scr + HW, dn, tid);
        for (int p = tid; p < HW; p += 256) dn[p] = __fdiv_rn(dn[p], dmax);
    }
    __syncthreads();

    // ---------------- init phase 1: conv1 LUT + zero ALL mask buffers --------
    for (int e = tid; e < 512; e += 256) {
        float a0 = 0.f, a1 = 0.f, a2 = 0.f, a3 = 0.f;
        #pragma unroll
        for (int k = 0; k < 9; ++k) {
            bool bit = (e >> k) & 1;
            a0 = fadd(a0, bit ? wts[k]      : 0.0f);
            a1 = fadd(a1, bit ? wts[9 + k]  : 0.0f);
            a2 = fadd(a2, bit ? wts[18 + k] : 0.0f);
            a3 = fadd(a3, bit ? wts[27 + k] : 0.0f);
        }
        lut[e] = make_float4(a0, a1, a2, a3);
    }
    for (int w = tid; w < 312; w += 256) {
        if (w < 84) s1m[w] = 0u;
        else if (w < 240) p1m[w - 84] = 0u;
        else p2m[w - 240] = 0u;
    }
    __syncthreads();

    // ---------------- per-thread constants ----------------
    float dnr[4];
    #pragma unroll
    for (int k = 0; k < 4; ++k) {
        int e = tid + (k << 8);
        dnr[k] = (e < HW) ? dn[e] : 0.f;
    }
    float w2r[36];
    #pragma unroll
    for (int m = 0; m < 36; ++m) w2r[m] = wts[36 + c2 * 36 + m];

    // ---------------- layer1(0) -> s1m buf 0 ----------------
    #pragma unroll
    for (int k = 0; k < 4; ++k) {
        if (k < 3 || tid < 16) {
            float v = fadd(v1m[k], dnr[k]);
            bool spk = v >= 4.5f;
            v1m[k] = spk ? 0.f : v;
            if (spk) atomicOr(&s1m[l1w_[k]], l1b_[k]);
        }
    }
    __syncthreads();

    const float* lutf = (const float*)lut;

    // ======== pipelined loop: ONE barrier per phase ========
    // phase t runs: conv1(t) | conv2(t-1) | conv3(t-2) | layer1(t+1) | zeroing
    int iA = 0, iB = 1, iC = 2;   // iA=t%3, iB=(t+1)%3, iC=(t+2)%3
    for (int t = 0; t < TSTEPS + 2; ++t) {
        const unsigned* s1r = s1m + iA * 28;   // read by conv1(t)
        unsigned*       s1w = s1m + iB * 28;   // written by layer1(t+1)
        unsigned*       s1z = s1m + iC * 28;   // zeroed (for t+2)
        unsigned*       p1w = p1m + iA * 52;   // written by conv1(t)
        unsigned*       p1z = p1m + iB * 52;   // zeroed (for t+1)
        const unsigned* p1r = p1m + iC * 52;   // read by conv2(t-1)
        unsigned*       p2z = p2m + iA * 24;   // zeroed (for t+1's conv2)
        const unsigned* p2r = p2m + iB * 24;   // read by conv3(t-2)
        unsigned*       p2w = p2m + iC * 24;   // written by conv2(t-1)

        // ---- conv3(t-2) : lanes 240..255 ----
        if (t >= 2 && tid >= 240) {
            int qq = tid - 240, rr = qq >> 2, cc = qq & 3;
            float acc = 0.f;
            #pragma unroll
            for (int ic = 0; ic < 4; ++ic)
                #pragma unroll
                for (int ki = 0; ki < 3; ++ki) {
                    unsigned rwv = p2r[ic * 6 + rr + ki] >> (unsigned)cc;
                    #pragma unroll
                    for (int kj = 0; kj < 3; ++kj)
                        acc = fadd(acc, SELW(rwv, kj, wts[180 + ic * 9 + ki * 3 + kj]));
                }
            v4 = fadd(v4, fmul(fsub(acc, v4), 0.5f));
            if (v4 >= 1.0f) { pred += 1.f; v4 = 0.f; }
        }

        // ---- conv1(t) : all threads, <=3 items ----
        if (t < TSTEPS) {
            #pragma unroll
            for (int k = 0; k < 3; ++k) {
                if (k < 2 || tid < 164) {
                    int sr = srow_[k], sh = sh1_[k];
                    unsigned m0 = s1r[sr], m1 = s1r[sr + 1],
                             m2 = s1r[sr + 2], m3 = s1r[sr + 3];
                    unsigned cb = 0;
                    #pragma unroll
                    for (int di = 0; di < 2; ++di) {
                        unsigned ra = di ? m1 : m0, rb = di ? m2 : m1, rc = di ? m3 : m2;
                        #pragma unroll
                        for (int dj = 0; dj < 2; ++dj) {
                            unsigned s = (unsigned)(sh + dj);
                            unsigned pat = UBFE(ra, s, 3) | (UBFE(rb, s, 3) << 3)
                                         | (UBFE(rc, s, 3) << 6);
                            float a = lutf[(pat << 2) + c1_[k]];
                            float v = fadd(v2q[k][di * 2 + dj], a);
                            bool spk = v >= 4.5f;
                            v2q[k][di * 2 + dj] = spk ? 0.f : v;
                            cb |= (unsigned)spk;
                        }
                    }
                    if (cb) atomicOr(&p1w[pw1_[k]], pb1_[k]);
                }
            }
        }

        // ---- conv2(t-1) : threads <244, <=2 cells ----
        if (t >= 1 && t < TSTEPS + 1) {
            #pragma unroll
            for (int k = 0; k < 2; ++k) {
                if (k == 0 ? cv2a : cv2b) {
                    int pr = prow_[k]; unsigned js = (unsigned)jsh_[k];
                    float acc = 0.f;
                    #pragma unroll
                    for (int ic = 0; ic < 4; ++ic) {
                        #pragma unroll
                        for (int ki = 0; ki < 3; ++ki) {
                            unsigned rwv = p1r[ic * 13 + pr + ki] >> js;
                            acc = fadd(acc, SELW(rwv, 0, w2r[ic * 9 + ki * 3 + 0]));
                            acc = fadd(acc, SELW(rwv, 1, w2r[ic * 9 + ki * 3 + 1]));
                            acc = fadd(acc, SELW(rwv, 2, w2r[ic * 9 + ki * 3 + 2]));
                        }
                    }
                    float v = fadd(v3m[k], acc);
                    bool spk = v >= 1.0f;
                    v3m[k] = spk ? 0.f : v;
                    if (spk) atomicOr(&p2w[p2w_[k]], p2b_[k]);
                }
            }
        }

        // ---- layer1(t+1) : all threads ----
        if (t < TSTEPS - 1) {
            #pragma unroll
            for (int k = 0; k < 4; ++k) {
                if (k < 3 || tid < 16) {
                    float v = fadd(v1m[k], dnr[k]);
                    bool spk = v >= 4.5f;
                    v1m[k] = spk ? 0.f : v;
                    if (spk) atomicOr(&s1w[l1w_[k]], l1b_[k]);
                }
            }
        }

        // ---- zero next-use buffers ----
        if (tid >= 164 && tid < 192) s1z[tid - 164] = 0u;
        if (tid >= 192 && tid < 244) p1z[tid - 192] = 0u;
        if (tid >= 164 && tid < 188) p2z[tid - 164] = 0u;

        __syncthreads();
        int tmp = iA; iA = iB; iB = iC; iC = tmp;
    }

    // ---------------- output ----------------
    if (tid >= 240) {
        int qq = tid - 240;
        out[(size_t)b * 16 + qq] = __fdiv_rn(pred, 30.0f);
    }
}

extern "C" void kernel_launch(void* const* d_in, const int* in_sizes, int n_in,
                              void* d_out, int out_size, void* d_ws, size_t ws_size,
                              hipStream_t stream) {
    const float* x  = (const float*)d_in[0];
    const float* w1 = (const float*)d_in[1];
    const float* w2 = (const float*)d_in[2];
    const float* w3 = (const float*)d_in[3];
    float* out = (float*)d_out;
    unsigned int* dmax = (unsigned int*)d_ws;
    float* dcache = (float*)((char*)d_ws + 16);

    int nbatch = in_sizes[0] / HW;
    size_t need = 16 + (size_t)nbatch * HW * sizeof(float);
    bool cache = ws_size >= need;

    // numpy-f32 Gaussian weights: exact f32 steps + correctly-rounded exp
    GaussW gw;
    {
        float fw[7];
        for (int k = 0; k < 7; ++k) {
            float iv = (float)(k - 3);
            float q = iv / 2.0f;
            float e = -0.5f * (q * q);
            fw[k] = (float)exp((double)e);
        }
        float s = 0.0f;
        for (int k = 0; k < 7; ++k) s += fw[k];
        for (int k = 0; k < 7; ++k) gw.w[k] = fw[k] / s;
    }

    hipLaunchKernelGGL(init_kernel, dim3(1), dim3(1), 0, stream, dmax);
    if (cache) {
        hipLaunchKernelGGL(dmax_kernel<true>, dim3(nbatch), dim3(256), 0, stream,
                           x, nbatch, gw, dmax, dcache);
        hipLaunchKernelGGL(sim_kernel<true>, dim3(nbatch), dim3(256), 0, stream,
                           x, nbatch, w1, w2, w3, gw, dmax, dcache, out);
    } else {
        hipLaunchKernelGGL(dmax_kernel<false>, dim3(nbatch), dim3(256), 0, stream,
                           x, nbatch, gw, dmax, dcache);
        hipLaunchKernelGGL(sim_kernel<false>, dim3(nbatch), dim3(256), 0, stream,
                           x, nbatch, w1, w2, w3, gw, dmax, dcache, out);
    }
}

// Round 9
// 288.354 us; speedup vs baseline: 1.8526x; 1.5273x over previous
//
#include <hip/hip_runtime.h>
#include <math.h>

#define HW 784      // 28*28
#define TSTEPS 30

struct GaussW { float w[7]; };

// Exact-rounded f32 ops (never fused/contracted) to bitwise-match numpy f32.
__device__ __forceinline__ float fadd(float a, float b) { return __fadd_rn(a, b); }
__device__ __forceinline__ float fmul(float a, float b) { return __fmul_rn(a, b); }
__device__ __forceinline__ float fsub(float a, float b) { return __fsub_rn(a, b); }

#if defined(__has_builtin)
#  if __has_builtin(__builtin_amdgcn_ubfe)
#    define UBFE(x, o, w) __builtin_amdgcn_ubfe((unsigned)(x), (unsigned)(o), (unsigned)(w))
#  endif
#endif
#ifndef UBFE
#  define UBFE(x, o, w) (((unsigned)(x) >> (o)) & ((1u << (w)) - 1u))
#endif

__device__ __forceinline__ int refl(int i, int n) {
    if (i < 0) return -i - 1;
    if (i >= n) return 2 * n - 1 - i;
    return i;
}

// d[p] = |gauss4d(x)[b,p] - x[b,p]| into dout (784 floats in LDS), bit-exact
// numpy-f32 order: axis0 (batch), axis1 (size-1 channel), axis2, axis3.
__device__ void dog_sample(const float* __restrict__ x, int b, int nbatch,
                           const GaussW gw, float* g, float* t,
                           float* dout, int tid) {
    for (int p = tid; p < HW; p += 256) {
        float acc = fmul(gw.w[0], x[(size_t)refl(b - 3, nbatch) * HW + p]);
        #pragma unroll
        for (int k = 1; k < 7; ++k)
            acc = fadd(acc, fmul(gw.w[k], x[(size_t)refl(b - 3 + k, nbatch) * HW + p]));
        float h = fmul(gw.w[0], acc);   // axis 1: size-1 dim, all slices equal
        #pragma unroll
        for (int k = 1; k < 7; ++k)
            h = fadd(h, fmul(gw.w[k], acc));
        g[p] = h;
    }
    __syncthreads();
    for (int p = tid; p < HW; p += 256) {
        int i = p / 28, j = p - (p / 28) * 28;
        float acc = fmul(gw.w[0], g[refl(i - 3, 28) * 28 + j]);
        #pragma unroll
        for (int k = 1; k < 7; ++k)
            acc = fadd(acc, fmul(gw.w[k], g[refl(i - 3 + k, 28) * 28 + j]));
        t[p] = acc;
    }
    __syncthreads();
    for (int p = tid; p < HW; p += 256) {
        int i = p / 28, j = p - (p / 28) * 28;
        float acc = fmul(gw.w[0], t[i * 28 + refl(j - 3, 28)]);
        #pragma unroll
        for (int k = 1; k < 7; ++k)
            acc = fadd(acc, fmul(gw.w[k], t[i * 28 + refl(j - 3 + k, 28)]));
        dout[p] = fabsf(fsub(acc, x[(size_t)b * HW + p]));
    }
    __syncthreads();
}

__global__ void init_kernel(unsigned int* dmax) { *dmax = 0u; }

template<bool CACHE>
__global__ __launch_bounds__(256) void dmax_kernel(const float* __restrict__ x,
                                                   int nbatch, GaussW gw,
                                                   unsigned int* __restrict__ dmax,
                                                   float* __restrict__ dcache) {
    __shared__ float g[HW], t[HW], d[HW];
    __shared__ float wred[4];
    int tid = threadIdx.x;
    int b = blockIdx.x;
    dog_sample(x, b, nbatch, gw, g, t, d, tid);
    if (CACHE)
        for (int p = tid; p < HW; p += 256) dcache[(size_t)b * HW + p] = d[p];
    float m = 0.f;
    for (int p = tid; p < HW; p += 256) m = fmaxf(m, d[p]);
    #pragma unroll
    for (int off = 32; off; off >>= 1) m = fmaxf(m, __shfl_down(m, off, 64));
    if ((tid & 63) == 0) wred[tid >> 6] = m;
    __syncthreads();
    if (tid == 0) {
        m = fmaxf(fmaxf(wred[0], wred[1]), fmaxf(wred[2], wred[3]));
        atomicMax(dmax, __float_as_uint(m));  // d >= 0 so bit-max == float-max
    }
}

template<bool CACHE>
__global__ __launch_bounds__(256) void sim_kernel(const float* __restrict__ x,
        int nbatch,
        const float* __restrict__ w1g, const float* __restrict__ w2g,
        const float* __restrict__ w3g, GaussW gw,
        const unsigned int* __restrict__ dmaxp,
        const float* __restrict__ dcache,
        float* __restrict__ out) {
    __shared__ __align__(16) float4 lut[512];   // conv1 LUT (4ch); DoG scratch pre-loop
    __shared__ __align__(8)  float2 lut2[768];  // conv2 row-pair LUT [cout][ic][ki][16]
    __shared__ float lut3[96];                  // conv3 row LUT [ic][ki][8]
    __shared__ __align__(16) float dn[HW];      // normalized DoG input
    __shared__ unsigned s1m[84];                // 3 bufs x 28 rows
    __shared__ unsigned p1m[156];               // 3 bufs x 52 (4c x 13r, bits<<1)
    __shared__ unsigned p2m[72];                // 3 bufs x 24 (4c x 6r)
    __shared__ float wts[216];                  // w1(36) | w2(144) | w3(36)

    int tid = threadIdx.x;
    int b = blockIdx.x;

    // ============ fixed geometry ============
    // conv2 pairs (tids < 128): items pA=tid, pB=tid+128 (valid <220)
    //   pair p: row=p/5 (0..43), j0=2*(p%5); c=row/11, i2=row%11
    bool isC2 = tid < 128;
    int pA = isC2 ? tid : 0;
    int pB = tid + 128;
    bool hasB = isC2 && (pB < 220);
    if (!hasB) pB = 0;
    int rA = pA / 5, j0A = 2 * (pA - rA * 5), cA = rA / 11, i2A = rA - (rA / 11) * 11;
    int rB = pB / 5, j0B = 2 * (pB - rB * 5), cB = rB / 11, i2B = rB - (rB / 11) * 11;
    int lbA = cA * 192, lbB = cB * 192;
    int p2wA = cA * 6 + ((i2A + 1) >> 1), p2wB = cB * 6 + ((i2B + 1) >> 1);
    unsigned bA0 = 1u << (j0A >> 1), bA1 = 2u << (j0A >> 1);
    unsigned bB0 = 1u << (j0B >> 1), bB1 = 2u << (j0B >> 1);
    // conv2 singles (tids 192..235): s=tid-192: c=s/11, i2=s%11, col 10
    bool isSg = (tid >= 192) && (tid < 236);
    int sS = isSg ? tid - 192 : 0;
    int cS = sS / 11, i2S = sS - (sS / 11) * 11;
    int lbS = cS * 192;
    int p2wS = cS * 6 + ((i2S + 1) >> 1);
    // conv1 quads (tids >= 128): g0=tid-128; g1=g0+128 (valid <169)
    int g0 = (tid >= 128) ? tid - 128 : 0;
    int q_sr[2], q_sh[2], q_pi[2]; unsigned q_bit[2]; bool q_ok[2];
    #pragma unroll
    for (int k = 0; k < 2; ++k) {
        int g = g0 + (k ? 128 : 0);
        q_ok[k] = (tid >= 128) && (g < 169);
        if (g >= 169) g = 0;
        int pi = g / 13, pj = g - pi * 13;
        q_sr[k] = 2 * pi; q_sh[k] = 2 * pj; q_pi[k] = pi;
        q_bit[k] = 1u << (pj + 1);
    }
    // layer1 (tids < 128): px = tid + 128k, k<7 (k=6: tid<16)
    int l1w_[7]; unsigned l1b_[7];
    #pragma unroll
    for (int k = 0; k < 7; ++k) {
        int e = tid + (k << 7); if (e >= HW) e = 0;
        int rw = e / 28;
        l1w_[k] = rw; l1b_[k] = 1u << (e - rw * 28);
    }
    // conv3 (tids >= 240)
    int qq = (tid >= 240) ? tid - 240 : 0;
    int rr3 = qq >> 2, cc3 = qq & 3;

    // ============ membranes (registers) ============
    float v2s[2][16] = {};                  // conv1 quads (tid>=128)
    float v3A[2] = {0.f, 0.f}, v3B[2] = {0.f, 0.f};  // conv2 pairs (tid<128)
    float v3S = 0.f;                        // conv2 single (tids 192-235)
    float v1m[7] = {};                      // layer1 (tid<128)
    float v4 = 0.f, pred = 0.f;             // LIF (tids 240-255)

    // ============ init phase 0: weights + dn ============
    if (tid < 36)  wts[tid]       = w1g[tid];
    if (tid < 144) wts[36 + tid]  = w2g[tid];
    if (tid < 36)  wts[180 + tid] = w3g[tid];
    float dmax = __uint_as_float(*dmaxp);
    if (CACHE) {
        for (int p = tid; p < HW; p += 256)
            dn[p] = __fdiv_rn(dcache[(size_t)b * HW + p], dmax);
    } else {
        float* scr = (float*)lut;   // 2048 floats >= 2*784
        dog_sample(x, b, nbatch, gw, scr, scr + HW, dn, tid);
        for (int p = tid; p < HW; p += 256) dn[p] = __fdiv_rn(dn[p], dmax);
    }
    __syncthreads();

    // ============ init phase 1: LUT builds + zero all masks ============
    for (int e = tid; e < 512; e += 256) {
        float a0 = 0.f, a1 = 0.f, a2 = 0.f, a3 = 0.f;
        #pragma unroll
        for (int k = 0; k < 9; ++k) {
            bool bit = (e >> k) & 1;
            a0 = fadd(a0, bit ? wts[k]      : 0.0f);
            a1 = fadd(a1, bit ? wts[9 + k]  : 0.0f);
            a2 = fadd(a2, bit ? wts[18 + k] : 0.0f);
            a3 = fadd(a3, bit ? wts[27 + k] : 0.0f);
        }
        lut[e] = make_float4(a0, a1, a2, a3);
    }
    for (int e = tid; e < 768; e += 256) {
        int rowIdx = e >> 4, idx = e & 15;
        int cout = rowIdx / 12, rem = rowIdx - cout * 12;
        int ic = rem / 3, ki = rem - ic * 3;
        const float* wb = &wts[36 + cout * 36 + ic * 9 + ki * 3];
        float xx = 0.f, yy = 0.f;
        #pragma unroll
        for (int kk = 0; kk < 3; ++kk) {
            xx = fadd(xx, ((idx >> kk) & 1) ? wb[kk] : 0.0f);
            yy = fadd(yy, ((idx >> (kk + 1)) & 1) ? wb[kk] : 0.0f);
        }
        lut2[e] = make_float2(xx, yy);
    }
    if (tid < 96) {
        int ric = tid >> 3, idx = tid & 7;
        int ic = ric / 3, ki = ric - ic * 3;
        const float* wb = &wts[180 + ic * 9 + ki * 3];
        float xx = 0.f;
        #pragma unroll
        for (int kk = 0; kk < 3; ++kk)
            xx = fadd(xx, ((idx >> kk) & 1) ? wb[kk] : 0.0f);
        lut3[tid] = xx;
    }
    for (int w = tid; w < 312; w += 256) {
        if (w < 84) s1m[w] = 0u;
        else if (w < 240) p1m[w - 84] = 0u;
        else p2m[w - 240] = 0u;
    }
    __syncthreads();

    // ============ per-thread constants ============
    float dnr[7];
    #pragma unroll
    for (int k = 0; k < 7; ++k) {
        int e = tid + (k << 7);
        dnr[k] = (isC2 && e < HW) ? dn[e] : 0.f;
    }

    // ============ layer1(0) -> s1m buf 0 ============
    if (isC2) {
        #pragma unroll
        for (int k = 0; k < 7; ++k) {
            if (k < 6 || tid < 16) {
                float v = fadd(v1m[k], dnr[k]);
                bool spk = v >= 4.5f;
                v1m[k] = spk ? 0.f : v;
                if (spk) atomicOr(&s1m[l1w_[k]], l1b_[k]);
            }
        }
    }
    __syncthreads();

    // ======== pipelined loop: one barrier per phase ========
    // phase t: conv1(t) | conv2(t-1) | conv3(t-2) | layer1(t+1) | zeroing
    int iA = 0, iB = 1, iC = 2;
    for (int t = 0; t < TSTEPS + 2; ++t) {
        const unsigned* s1r = s1m + iA * 28;
        unsigned*       s1w = s1m + iB * 28;
        unsigned*       s1z = s1m + iC * 28;
        unsigned*       p1w = p1m + iA * 52;
        unsigned*       p1z = p1m + iB * 52;
        const unsigned* p1r = p1m + iC * 52;
        unsigned*       p2z = p2m + iA * 24;
        const unsigned* p2r = p2m + iB * 24;
        unsigned*       p2w = p2m + iC * 24;

        // ---- conv3(t-2): tids 240-255 ----
        if (t >= 2 && tid >= 240) {
            float acc = 0.f;
            #pragma unroll
            for (int ic = 0; ic < 4; ++ic)
                #pragma unroll
                for (int ki = 0; ki < 3; ++ki) {
                    unsigned row = p2r[ic * 6 + rr3 + ki];
                    unsigned idx = UBFE(row, cc3, 3);
                    acc = fadd(acc, lut3[(ic * 3 + ki) * 8 + idx]);
                }
            v4 = fadd(v4, fmul(fsub(acc, v4), 0.5f));
            if (v4 >= 1.0f) { pred += 1.f; v4 = 0.f; }
        }

        // ---- conv1(t): tids >= 128, up to 2 quads ----
        if (t < TSTEPS && tid >= 128) {
            #pragma unroll
            for (int k = 0; k < 2; ++k) {
                if (q_ok[k]) {
                    int sr = q_sr[k], sh = q_sh[k], pi = q_pi[k];
                    unsigned m0 = s1r[sr], m1 = s1r[sr + 1],
                             m2 = s1r[sr + 2], m3 = s1r[sr + 3];
                    unsigned a = UBFE(m0, sh, 4), bq = UBFE(m1, sh, 4),
                             cq = UBFE(m2, sh, 4), dq = UBFE(m3, sh, 4);
                    unsigned a7 = a & 7u, b7 = bq & 7u, c7 = cq & 7u, d7 = dq & 7u;
                    unsigned a1 = a >> 1, b1 = bq >> 1, c1 = cq >> 1, d1 = dq >> 1;
                    unsigned p00 = a7 | (b7 << 3) | (c7 << 6);
                    unsigned p01 = a1 | (b1 << 3) | (c1 << 6);
                    unsigned p10 = b7 | (c7 << 3) | (d7 << 6);
                    unsigned p11 = b1 | (c1 << 3) | (d1 << 6);
                    float4 e00 = lut[p00], e01 = lut[p01];
                    float4 e10 = lut[p10], e11 = lut[p11];
                    unsigned cb0 = 0, cb1 = 0, cb2 = 0, cb3 = 0;
                    #define CELL1(E, ci) { float v; bool s; \
                        v = fadd(v2s[k][(ci)*4+0], E.x); s = v>=4.5f; v2s[k][(ci)*4+0] = s?0.f:v; cb0 |= (unsigned)s; \
                        v = fadd(v2s[k][(ci)*4+1], E.y); s = v>=4.5f; v2s[k][(ci)*4+1] = s?0.f:v; cb1 |= (unsigned)s; \
                        v = fadd(v2s[k][(ci)*4+2], E.z); s = v>=4.5f; v2s[k][(ci)*4+2] = s?0.f:v; cb2 |= (unsigned)s; \
                        v = fadd(v2s[k][(ci)*4+3], E.w); s = v>=4.5f; v2s[k][(ci)*4+3] = s?0.f:v; cb3 |= (unsigned)s; }
                    CELL1(e00, 0) CELL1(e01, 1) CELL1(e10, 2) CELL1(e11, 3)
                    #undef CELL1
                    unsigned bitp = q_bit[k];
                    if (cb0) atomicOr(&p1w[pi],      bitp);
                    if (cb1) atomicOr(&p1w[13 + pi], bitp);
                    if (cb2) atomicOr(&p1w[26 + pi], bitp);
                    if (cb3) atomicOr(&p1w[39 + pi], bitp);
                }
            }
        }

        bool c2on = (t >= 1) && (t < TSTEPS + 1);

        // ---- conv2 pairs (t-1): tids < 128 ----
        if (c2on && isC2) {
            {   // item A
                float accA = 0.f, accB = 0.f;
                unsigned js = (unsigned)(j0A + 1);
                #pragma unroll
                for (int ic = 0; ic < 4; ++ic)
                    #pragma unroll
                    for (int ki = 0; ki < 3; ++ki) {
                        unsigned row = p1r[ic * 13 + i2A + ki];
                        unsigned idx = UBFE(row, js, 4);
                        float2 e = lut2[lbA + (ic * 3 + ki) * 16 + idx];
                        accA = fadd(accA, e.x);
                        accB = fadd(accB, e.y);
                    }
                float va = fadd(v3A[0], accA);
                float vb = fadd(v3A[1], accB);
                bool sa = va >= 1.0f, sb = vb >= 1.0f;
                v3A[0] = sa ? 0.f : va; v3A[1] = sb ? 0.f : vb;
                unsigned orm = (sa ? bA0 : 0u) | (sb ? bA1 : 0u);
                if (orm) atomicOr(&p2w[p2wA], orm);
            }
            if (hasB) {   // item B
                float accA = 0.f, accB = 0.f;
                unsigned js = (unsigned)(j0B + 1);
                #pragma unroll
                for (int ic = 0; ic < 4; ++ic)
                    #pragma unroll
                    for (int ki = 0; ki < 3; ++ki) {
                        unsigned row = p1r[ic * 13 + i2B + ki];
                        unsigned idx = UBFE(row, js, 4);
                        float2 e = lut2[lbB + (ic * 3 + ki) * 16 + idx];
                        accA = fadd(accA, e.x);
                        accB = fadd(accB, e.y);
                    }
                float va = fadd(v3B[0], accA);
                float vb = fadd(v3B[1], accB);
                bool sa = va >= 1.0f, sb = vb >= 1.0f;
                v3B[0] = sa ? 0.f : va; v3B[1] = sb ? 0.f : vb;
                unsigned orm = (sa ? bB0 : 0u) | (sb ? bB1 : 0u);
                if (orm) atomicOr(&p2w[p2wB], orm);
            }
        }

        // ---- conv2 singles (t-1): tids 192-235, col 10 ----
        if (c2on && isSg) {
            float acc = 0.f;
            #pragma unroll
            for (int ic = 0; ic < 4; ++ic)
                #pragma unroll
                for (int ki = 0; ki < 3; ++ki) {
                    unsigned row = p1r[ic * 13 + i2S + ki];
                    unsigned idx = UBFE(row, 11, 4);
                    acc = fadd(acc, lut2[lbS + (ic * 3 + ki) * 16 + idx].x);
                }
            float v = fadd(v3S, acc);
            bool s = v >= 1.0f;
            v3S = s ? 0.f : v;
            if (s) atomicOr(&p2w[p2wS], 32u);   // bit (10+1)>>1 = 5
        }

        // ---- layer1(t+1): tids < 128 ----
        if (t < TSTEPS - 1 && isC2) {
            #pragma unroll
            for (int k = 0; k < 7; ++k) {
                if (k < 6 || tid < 16) {
                    float v = fadd(v1m[k], dnr[k]);
                    bool spk = v >= 4.5f;
                    v1m[k] = spk ? 0.f : v;
                    if (spk) atomicOr(&s1w[l1w_[k]], l1b_[k]);
                }
            }
        }

        // ---- zero next-use buffers: tids 169-191 ----
        if (tid >= 169 && tid < 192) {
            for (int w = tid - 169; w < 104; w += 23) {
                if (w < 28) s1z[w] = 0u;
                else if (w < 80) p1z[w - 28] = 0u;
                else p2z[w - 80] = 0u;
            }
        }

        __syncthreads();
        int tmp = iA; iA = iB; iB = iC; iC = tmp;
    }

    // ============ output ============
    if (tid >= 240) {
        out[(size_t)b * 16 + (tid - 240)] = __fdiv_rn(pred, 30.0f);
    }
}

extern "C" void kernel_launch(void* const* d_in, const int* in_sizes, int n_in,
                              void* d_out, int out_size, void* d_ws, size_t ws_size,
                              hipStream_t stream) {
    const float* x  = (const float*)d_in[0];
    const float* w1 = (const float*)d_in[1];
    const float* w2 = (const float*)d_in[2];
    const float* w3 = (const float*)d_in[3];
    float* out = (float*)d_out;
    unsigned int* dmax = (unsigned int*)d_ws;
    float* dcache = (float*)((char*)d_ws + 16);

    int nbatch = in_sizes[0] / HW;
    size_t need = 16 + (size_t)nbatch * HW * sizeof(float);
    bool cache = ws_size >= need;

    // numpy-f32 Gaussian weights: exact f32 steps + correctly-rounded exp
    GaussW gw;
    {
        float fw[7];
        for (int k = 0; k < 7; ++k) {
            float iv = (float)(k - 3);
            float q = iv / 2.0f;
            float e = -0.5f * (q * q);
            fw[k] = (float)exp((double)e);
        }
        float s = 0.0f;
        for (int k = 0; k < 7; ++k) s += fw[k];
        for (int k = 0; k < 7; ++k) gw.w[k] = fw[k] / s;
    }

    hipLaunchKernelGGL(init_kernel, dim3(1), dim3(1), 0, stream, dmax);
    if (cache) {
        hipLaunchKernelGGL(dmax_kernel<true>, dim3(nbatch), dim3(256), 0, stream,
                           x, nbatch, gw, dmax, dcache);
        hipLaunchKernelGGL(sim_kernel<true>, dim3(nbatch), dim3(256), 0, stream,
                           x, nbatch, w1, w2, w3, gw, dmax, dcache, out);
    } else {
        hipLaunchKernelGGL(dmax_kernel<false>, dim3(nbatch), dim3(256), 0, stream,
                           x, nbatch, gw, dmax, dcache);
        hipLaunchKernelGGL(sim_kernel<false>, dim3(nbatch), dim3(256), 0, stream,
                           x, nbatch, w1, w2, w3, gw, dmax, dcache, out);
    }
}